// Round 9
// baseline (270.160 us; speedup 1.0000x reference)
//
#include <hip/hip_runtime.h>
#include <hip/hip_bf16.h>
#include <math.h>

typedef unsigned short u16;
typedef __attribute__((ext_vector_type(8))) short bf16x8;
typedef __attribute__((ext_vector_type(4))) float f32x4;
typedef __attribute__((ext_vector_type(4))) unsigned short u16x4;

#define B_ 8
#define S_ 2048
#define T_ 16384
#define D_ 1024
#define H_ 16
#define EPS_ 1e-5f

__device__ __forceinline__ u16 f2bf(float f) {
    __hip_bfloat16 h = __float2bfloat16(f);
    union { __hip_bfloat16 h; u16 u; } cv; cv.h = h; return cv.u;
}
__device__ __forceinline__ float bf2f(u16 u) {
    union { u16 u; __hip_bfloat16 h; } cv; cv.u = u; return __bfloat162float(cv.h);
}

// ---------- k01: fused {k1 pool-LN pass (blocks 0..255)} U {k0a W' split (blocks 256..767)} ----------
__global__ __launch_bounds__(256) void k01(const float* __restrict__ x,
        u16* __restrict__ xhi, u16* __restrict__ xlo,
        float* __restrict__ sx, float* __restrict__ sxx, float* __restrict__ gpart,
        const float* __restrict__ rw1, const float* __restrict__ rlng,
        const float* __restrict__ rlnb, u16* __restrict__ whiT, u16* __restrict__ wloT,
        float* __restrict__ c1part, float* __restrict__ c2part) {
    __shared__ float lacc[4][1024];                    // k1 use
    __shared__ float ld[64][65];                       // k0a use
    __shared__ float red[2][4][64];
    int blk = blockIdx.x;
    int tid = threadIdx.x;
    if (blk < 256) {
        // ----- k1: pool LN pass, per-token sums, x -> split bf16 -----
        int b = blk >> 5, chunk = blk & 31;
        int w = tid >> 6, lane = tid & 63;
        float acc[4][4];
        #pragma unroll
        for (int j = 0; j < 4; ++j)
            #pragma unroll
            for (int c = 0; c < 4; ++c) acc[j][c] = 0.f;
        for (int i = 0; i < 16; ++i) {
            int s = chunk * 64 + i * 4 + w;
            size_t tok = (size_t)b * S_ + s;
            size_t base = tok * D_;
            float4 v[4];
            float sum = 0.f, ssq = 0.f;
            #pragma unroll
            for (int j = 0; j < 4; ++j) {
                v[j] = *(const float4*)&x[base + j * 256 + lane * 4];
                sum += v[j].x + v[j].y + v[j].z + v[j].w;
                ssq += v[j].x * v[j].x + v[j].y * v[j].y + v[j].z * v[j].z + v[j].w * v[j].w;
            }
            #pragma unroll
            for (int m = 1; m < 64; m <<= 1) { sum += __shfl_xor(sum, m); ssq += __shfl_xor(ssq, m); }
            float mean = sum * (1.f / 1024.f);
            float var = ssq * (1.f / 1024.f) - mean * mean;
            float rstd = rsqrtf(var + EPS_);
            if (lane == 0) { sx[tok] = sum; sxx[tok] = ssq; }
            #pragma unroll
            for (int j = 0; j < 4; ++j) {
                float xs[4] = { v[j].x, v[j].y, v[j].z, v[j].w };
                u16 hs[4], ls[4];
                #pragma unroll
                for (int c = 0; c < 4; ++c) {
                    acc[j][c] += (xs[c] - mean) * rstd;
                    u16 h = f2bf(xs[c]);
                    hs[c] = h;
                    ls[c] = f2bf(xs[c] - bf2f(h));
                }
                size_t o = base + j * 256 + lane * 4;
                *(u16x4*)&xhi[o] = (u16x4){ hs[0], hs[1], hs[2], hs[3] };
                *(u16x4*)&xlo[o] = (u16x4){ ls[0], ls[1], ls[2], ls[3] };
            }
        }
        #pragma unroll
        for (int j = 0; j < 4; ++j)
            #pragma unroll
            for (int c = 0; c < 4; ++c) lacc[w][j * 256 + lane * 4 + c] = acc[j][c];
        __syncthreads();
        for (int q = 0; q < 4; ++q) {
            int n = q * 256 + tid;
            gpart[((size_t)b * 32 + chunk) * 1024 + n] =
                lacc[0][n] + lacc[1][n] + lacc[2][n] + lacc[3][n];
        }
    } else {
        // ----- k0a: W' transpose+split, c1/c2 partials -----
        int idx = blk - 256;
        int nb = idx & 15, kb = idx >> 4;
        int nl = tid & 63, kq = tid >> 6;
        int n0 = nb * 64, k0 = kb * 64;
        float a1 = 0.f, a2 = 0.f;
        #pragma unroll
        for (int r = 0; r < 16; ++r) {
            int kl = r * 4 + kq;
            int k = k0 + kl, n = n0 + nl;
            float w0 = rw1[(size_t)k * 1024 + n];
            ld[kl][nl] = w0;
            a1 += rlng[k] * w0;
            a2 += rlnb[k] * w0;
        }
        red[0][kq][nl] = a1;
        red[1][kq][nl] = a2;
        __syncthreads();
        if (tid < 64) {
            c1part[(size_t)kb * 1024 + n0 + tid] = red[0][0][tid] + red[0][1][tid] + red[0][2][tid] + red[0][3][tid];
            c2part[(size_t)kb * 1024 + n0 + tid] = red[1][0][tid] + red[1][1][tid] + red[1][2][tid] + red[1][3][tid];
        }
        if (kb < 16) {
            #pragma unroll
            for (int r = 0; r < 16; ++r) {
                int nl2 = r * 4 + kq;
                int k = k0 + nl, n = n0 + nl2;
                float w0 = ld[nl][nl2] * rlng[k];
                u16 hi = f2bf(w0);
                float lo = w0 - bf2f(hi);
                whiT[(size_t)n * 1024 + k] = hi;
                wloT[(size_t)n * 1024 + k] = f2bf(lo);
            }
        }
    }
}

// ---------- kB: {kgemv_g split-K GEMV (blocks 0..127)} U {c1/dvec reduce (128..131)} ----------
__global__ __launch_bounds__(256) void kB(const float* __restrict__ gpart,
        const float* __restrict__ pg, const float* __restrict__ pb,
        const float* __restrict__ W, float* __restrict__ part,
        const float* __restrict__ c1part, const float* __restrict__ c2part,
        const float* __restrict__ rb1, float* __restrict__ c1, float* __restrict__ dvec) {
    int blk = blockIdx.x, t = threadIdx.x;
    if (blk < 128) {
        int nBlk = blk & 3, ks = blk >> 2;
        int n = nBlk * 256 + t;
        int k0 = ks * 32;
        __shared__ float sg[8][32];
        {
            int b = t >> 5, k = t & 31;
            float s = 0.f;
            #pragma unroll 8
            for (int p = 0; p < 32; ++p) s += gpart[((size_t)b * 32 + p) * 1024 + k0 + k];
            sg[b][k] = s * (1.f / 2048.f) * pg[k0 + k] + pb[k0 + k];
        }
        __syncthreads();
        float acc[8] = {};
        #pragma unroll
        for (int k = 0; k < 32; ++k) {
            float wv = W[(size_t)(k0 + k) * 1024 + n];
            #pragma unroll
            for (int b = 0; b < 8; ++b) acc[b] += sg[b][k] * wv;
        }
        #pragma unroll
        for (int b = 0; b < 8; ++b)
            part[((size_t)ks * 8 + b) * 1024 + n] = acc[b];
    } else {
        int n = (blk - 128) * 256 + t;
        float s1 = 0.f, s2 = 0.f;
        for (int p = 0; p < 32; ++p) { s1 += c1part[p * 1024 + n]; s2 += c2part[p * 1024 + n]; }
        c1[n] = s1;
        dvec[n] = s2 + rb1[n];
    }
}

// ---------- kgemv2_f: fused xctrl reduce(+bias) + dual split-K GEMV for W_z / W_h ----------
__global__ __launch_bounds__(256) void kgemv2_f(const float* __restrict__ partIn,
        const float* __restrict__ bias,
        const float* __restrict__ Wz, const float* __restrict__ Wh,
        float* __restrict__ zpart, float* __restrict__ hpart) {
    int t = threadIdx.x;
    int n = blockIdx.x * 256 + t;
    int k0 = blockIdx.y * 32;
    __shared__ float sg[8][32];
    {
        int b = t >> 5, k = t & 31;
        float s = bias[k0 + k];
        #pragma unroll 8
        for (int p = 0; p < 32; ++p) s += partIn[((size_t)p * 8 + b) * 1024 + k0 + k];
        sg[b][k] = s;
    }
    __syncthreads();
    float az[8] = {}, ah[8] = {};
    #pragma unroll
    for (int k = 0; k < 32; ++k) {
        size_t o = (size_t)(k0 + k) * 1024 + n;
        float wz = Wz[o];
        float wh = Wh[o];
        #pragma unroll
        for (int b = 0; b < 8; ++b) { az[b] += sg[b][k] * wz; ah[b] += sg[b][k] * wh; }
    }
    #pragma unroll
    for (int b = 0; b < 8; ++b) {
        size_t o = ((size_t)blockIdx.y * 8 + b) * 1024 + n;
        zpart[o] = az[b];
        hpart[o] = ah[b];
    }
}

// ---------- k3b reduce + gate + h-LayerNorm fused (grid 8, one block per b) ----------
__global__ __launch_bounds__(256) void k3b_red_ln(const float* __restrict__ zpart,
        const float* __restrict__ hpart, const float* __restrict__ bz,
        const float* __restrict__ bh, const float* __restrict__ state,
        const float* __restrict__ lg, const float* __restrict__ lb,
        float* __restrict__ hnew, float* __restrict__ outh,
        float* __restrict__ shb, float* __restrict__ shhb) {
    int b = blockIdx.x, tid = threadIdx.x;
    int w = tid >> 6, lane = tid & 63;
    __shared__ float rbuf[4][2];
    float hp[4];
    float sum = 0.f, ssq = 0.f;
    #pragma unroll
    for (int q = 0; q < 4; ++q) {
        int n = q * 256 + tid;
        float az = bz[n], ah = bh[n];
        #pragma unroll 8
        for (int p = 0; p < 32; ++p) {
            size_t o = ((size_t)p * 8 + b) * 1024 + n;
            az += zpart[o];
            ah += hpart[o];
        }
        float z = 1.f / (1.f + expf(-az));
        float hc = tanhf(ah);
        float v = (1.f - z) * state[(size_t)b * 1024 + n] + z * hc;
        hp[q] = v; sum += v; ssq += v * v;
    }
    #pragma unroll
    for (int m = 1; m < 64; m <<= 1) { sum += __shfl_xor(sum, m); ssq += __shfl_xor(ssq, m); }
    if (lane == 0) { rbuf[w][0] = sum; rbuf[w][1] = ssq; }
    __syncthreads();
    sum = rbuf[0][0] + rbuf[1][0] + rbuf[2][0] + rbuf[3][0];
    ssq = rbuf[0][1] + rbuf[1][1] + rbuf[2][1] + rbuf[3][1];
    float mean = sum * (1.f / 1024.f);
    float var = ssq * (1.f / 1024.f) - mean * mean;
    float rstd = rsqrtf(var + EPS_);
    float s2 = 0.f, q2 = 0.f;
    #pragma unroll
    for (int q = 0; q < 4; ++q) {
        int n = q * 256 + tid;
        float h = (hp[q] - mean) * rstd * lg[n] + lb[n];
        hnew[(size_t)b * 1024 + n] = h;
        outh[(size_t)b * 1024 + n] = h;
        s2 += h; q2 += h * h;
    }
    #pragma unroll
    for (int m = 1; m < 64; m <<= 1) { s2 += __shfl_xor(s2, m); q2 += __shfl_xor(q2, m); }
    __syncthreads();
    if (lane == 0) { rbuf[w][0] = s2; rbuf[w][1] = q2; }
    __syncthreads();
    if (tid == 0) {
        shb[b] = rbuf[0][0] + rbuf[1][0] + rbuf[2][0] + rbuf[3][0];
        shhb[b] = rbuf[0][1] + rbuf[1][1] + rbuf[2][1] + rbuf[3][1];
    }
}

// ---------- kE: {kgemv_split vmat partials (blocks 0..127)} U {pt/qt (128..191)} ----------
__global__ __launch_bounds__(256) void kE(const float* __restrict__ in,
        const float* __restrict__ W, const float* __restrict__ scale,
        float* __restrict__ part,
        const float* __restrict__ sx, const float* __restrict__ sxx,
        const float* __restrict__ shb, const float* __restrict__ shhb,
        float* __restrict__ pt, float* __restrict__ qt) {
    int blk = blockIdx.x, t = threadIdx.x;
    if (blk < 128) {
        int nBlk = blk & 3, ks = blk >> 2;
        int n = nBlk * 256 + t;
        int k0 = ks * 32;
        __shared__ float sg[8][32];
        {
            int b = t >> 5, k = t & 31;
            sg[b][k] = in[b * 1024 + k0 + k] * scale[k0 + k];
        }
        __syncthreads();
        float acc[8] = {};
        #pragma unroll
        for (int k = 0; k < 32; ++k) {
            float wv = W[(size_t)(k0 + k) * 1024 + n];
            #pragma unroll
            for (int b = 0; b < 8; ++b) acc[b] += sg[b][k] * wv;
        }
        #pragma unroll
        for (int b = 0; b < 8; ++b)
            part[((size_t)ks * 8 + b) * 1024 + n] = acc[b];
    } else {
        int tok = (blk - 128) * 256 + t;
        int b = tok >> 11;
        float m = (sx[tok] + shb[b]) * (1.f / 2048.f);
        float var = (sxx[tok] + shhb[b]) * (1.f / 2048.f) - m * m;
        float rstd = rsqrtf(var + EPS_);
        pt[tok] = rstd;
        qt[tok] = -m * rstd;
    }
}

// ---------- kF: vmat = reduce vmat partials (grid 32) ----------
__global__ __launch_bounds__(256) void kF(const float* __restrict__ part,
        float* __restrict__ vmat) {
    int i = blockIdx.x * 256 + threadIdx.x;
    int b = i >> 10, n = i & 1023;
    float s = 0.f;
    #pragma unroll 8
    for (int p = 0; p < 32; ++p) s += part[((size_t)p * 8 + b) * 1024 + n];
    vmat[i] = s;
}

// ---------- K5: split-bf16 MFMA GEMM, A-staged (swizzled) + B-direct-from-L2,
//   128x128 tile, BK=64, 2-barrier K-loop, LDS 33KB (4 blocks/CU), chunked epilogue ----------
__device__ __forceinline__ void gl16(const void* g, void* l) {
    __builtin_amdgcn_global_load_lds((const __attribute__((address_space(1))) void*)g,
                                     (__attribute__((address_space(3))) void*)l, 16, 0, 0);
}

__global__ __launch_bounds__(256, 1) void k5_gemm(
        const u16* __restrict__ xhi, const u16* __restrict__ xlo,
        const u16* __restrict__ whiT, const u16* __restrict__ wloT,
        const float* __restrict__ pt, const float* __restrict__ qt,
        const float* __restrict__ vmat, const float* __restrict__ c1,
        const float* __restrict__ dvec, const float* __restrict__ rw2,
        float* __restrict__ lpart) {
    // LDS: A-staging sAh(16KB)+sAl(16KB) = 32KB; epilogue reuse shid[64][129] = 33KB
    __shared__ unsigned char smem[33024];
    u16* sAh = (u16*)smem;
    u16* sAl = sAh + 128 * 64;
    float* shid = (float*)smem;

    // XCD-bijective remap: XCD x=bid%8 owns mb in [x*16,x*16+16); nb consecutive
    int bid = blockIdx.x;                   // 1024
    int x8 = bid & 7, j = bid >> 3;
    int mb = x8 * 16 + (j >> 3);            // 0..127
    int nb = j & 7;                         // 0..7
    int tid = threadIdx.x;
    int lane = tid & 63, wid = tid >> 6;
    int wm = wid >> 1, wn = wid & 1;
    int l16 = lane & 15, lq = lane >> 4;

    f32x4 acc[4][4] = {};

    size_t aBase = (size_t)mb * 128 * 1024;
    size_t bBase = (size_t)nb * 128 * 1024;

    for (int kb = 0; kb < 16; ++kb) {
        __syncthreads();
        #pragma unroll
        for (int i = 0; i < 4; ++i) {
            int chunk = tid + 256 * i;          // 1024 chunks of 16B per plane
            int row = chunk >> 3, c8 = chunk & 7;
            int s8 = c8 ^ (row & 7);            // involution slot-swizzle
            size_t go = (size_t)row * 1024 + (size_t)kb * 64 + s8 * 8;
            gl16(xhi + aBase + go, (char*)sAh + chunk * 16);
            gl16(xlo + aBase + go, (char*)sAl + chunk * 16);
        }
        asm volatile("s_waitcnt vmcnt(0)" ::: "memory");
        __syncthreads();
        #pragma unroll
        for (int kk = 0; kk < 2; ++kk) {
            bf16x8 ah[4], al[4], bh[4], bl[4];
            int sl = ((kk * 4 + lq) ^ (l16 & 7)) * 8;   // swizzled A slot
            #pragma unroll
            for (int f = 0; f < 4; ++f) {
                int ar = wm * 64 + f * 16 + l16;
                int br = wn * 64 + f * 16 + l16;
                size_t gb = bBase + (size_t)br * 1024 + (size_t)kb * 64 + kk * 32 + lq * 8;
                ah[f] = *(const bf16x8*)&sAh[ar * 64 + sl];
                al[f] = *(const bf16x8*)&sAl[ar * 64 + sl];
                bh[f] = *(const bf16x8*)&whiT[gb];      // B direct from L2
                bl[f] = *(const bf16x8*)&wloT[gb];
            }
            #pragma unroll
            for (int mf = 0; mf < 4; ++mf)
                #pragma unroll
                for (int nf = 0; nf < 4; ++nf) {
                    acc[mf][nf] = __builtin_amdgcn_mfma_f32_16x16x32_bf16(ah[mf], bh[nf], acc[mf][nf], 0, 0, 0);
                    acc[mf][nf] = __builtin_amdgcn_mfma_f32_16x16x32_bf16(ah[mf], bl[nf], acc[mf][nf], 0, 0, 0);
                    acc[mf][nf] = __builtin_amdgcn_mfma_f32_16x16x32_bf16(al[mf], bh[nf], acc[mf][nf], 0, 0, 0);
                }
        }
    }

    // ---- chunked epilogue: 2 chunks x 64 rows (chunk c written by waves wm==c) ----
    int token0 = mb * 128;
    int bidx = token0 >> 11;
    const float* vrow = vmat + (size_t)bidx * 1024;
    float vn[4], c1n[4], dn[4];
    #pragma unroll
    for (int nf = 0; nf < 4; ++nf) {
        int n = nb * 128 + wn * 64 + nf * 16 + l16;
        vn[nf] = vrow[n]; c1n[nf] = c1[n]; dn[nf] = dvec[n];
    }
    #pragma unroll
    for (int c = 0; c < 2; ++c) {
        __syncthreads();
        if (wm == c) {
            #pragma unroll
            for (int mf = 0; mf < 4; ++mf) {
                #pragma unroll
                for (int r = 0; r < 4; ++r) {
                    int rloc = mf * 16 + lq * 4 + r;        // 0..63
                    int tok = token0 + c * 64 + rloc;
                    float p = pt[tok];
                    float q = qt[tok];
                    #pragma unroll
                    for (int nf = 0; nf < 4; ++nf) {
                        int coll = wn * 64 + nf * 16 + l16;
                        float pre = p * (acc[mf][nf][r] + vn[nf]) + q * c1n[nf] + dn[nf];
                        shid[rloc * 129 + coll] = 0.5f * pre * (1.f + erff(pre * 0.70710678118f));
                    }
                }
            }
        }
        __syncthreads();
        // partial logits for rows [c*64, c*64+64): 4 threads per row, 4 heads each
        int rloc = tid >> 2, q4 = tid & 3;
        const float* w2b = rw2 + (size_t)nb * 128 * 16 + q4 * 4;
        float a4[4] = {};
        #pragma unroll 8
        for (int jj = 0; jj < 128; ++jj) {
            float hv = shid[rloc * 129 + jj];
            float4 w = *(const float4*)(w2b + (size_t)jj * 16);
            a4[0] += hv * w.x; a4[1] += hv * w.y; a4[2] += hv * w.z; a4[3] += hv * w.w;
        }
        float* lp = lpart + ((size_t)nb * T_ + token0 + c * 64 + rloc) * 16 + q4 * 4;
        lp[0] = a4[0]; lp[1] = a4[1]; lp[2] = a4[2]; lp[3] = a4[3];
    }
}

// ---------- K6: sum partials -> logits -> softmax -> top4 renorm -> alpha, entropy partials ----------
__global__ __launch_bounds__(256) void k6(const float* __restrict__ lpart,
        const float* __restrict__ rb2, float* __restrict__ alpha_out,
        float* __restrict__ entpart) {
    int blk = blockIdx.x;   // 1024
    int tid = threadIdx.x;
    int token = blk * 16 + (tid >> 4);
    int h = tid & 15;
    float lg = rb2[h];
    #pragma unroll
    for (int p = 0; p < 8; ++p) lg += lpart[((size_t)p * T_ + token) * 16 + h];

    float mx = lg;
    #pragma unroll
    for (int m = 1; m < 16; m <<= 1) mx = fmaxf(mx, __shfl_xor(mx, m));
    float e = expf(lg - mx);
    float sum = e;
    #pragma unroll
    for (int m = 1; m < 16; m <<= 1) sum += __shfl_xor(sum, m);
    float a0 = e / sum;

    float work = lg;
    bool sel = false;
    #pragma unroll
    for (int it = 0; it < 4; ++it) {
        float bv = work; int bi = h;
        #pragma unroll
        for (int m = 1; m < 16; m <<= 1) {
            float ov = __shfl_xor(bv, m); int oi = __shfl_xor(bi, m);
            if (ov > bv || (ov == bv && oi < bi)) { bv = ov; bi = oi; }
        }
        if (h == bi) { sel = true; work = -1e30f; }
    }
    float am = sel ? a0 : 0.f;
    float den = am;
    #pragma unroll
    for (int m = 1; m < 16; m <<= 1) den += __shfl_xor(den, m);
    den = fmaxf(den, 1e-12f);
    float a = am / den;
    alpha_out[(size_t)token * 16 + h] = a;

    float term = a * logf(fmaxf(a, 1e-12f));
    #pragma unroll
    for (int m = 1; m < 64; m <<= 1) term += __shfl_xor(term, m);
    __shared__ float tw[4];
    if ((tid & 63) == 0) tw[tid >> 6] = term;
    __syncthreads();
    if (tid == 0) entpart[blk] = tw[0] + tw[1] + tw[2] + tw[3];
}

// ---------- K7: entropy finalize ----------
__global__ __launch_bounds__(256) void k7(const float* __restrict__ entpart,
        float* __restrict__ out_ent) {
    int tid = threadIdx.x;
    float s = 0.f;
    for (int i = tid; i < 1024; i += 256) s += entpart[i];
    #pragma unroll
    for (int m = 1; m < 64; m <<= 1) s += __shfl_xor(s, m);
    __shared__ float tw[4];
    if ((tid & 63) == 0) tw[tid >> 6] = s;
    __syncthreads();
    if (tid == 0) out_ent[0] = -(tw[0] + tw[1] + tw[2] + tw[3]) * (1.f / (float)T_);
}

extern "C" void kernel_launch(void* const* d_in, const int* in_sizes, int n_in,
                              void* d_out, int out_size, void* d_ws, size_t ws_size,
                              hipStream_t stream) {
    const float* x     = (const float*)d_in[0];
    const float* state = (const float*)d_in[1];
    const float* pg    = (const float*)d_in[2];
    const float* pbv   = (const float*)d_in[3];
    const float* inpw  = (const float*)d_in[4];
    const float* inpb  = (const float*)d_in[5];
    const float* wzw   = (const float*)d_in[6];
    const float* wzb   = (const float*)d_in[7];
    const float* whw   = (const float*)d_in[8];
    const float* whb   = (const float*)d_in[9];
    const float* lnhg  = (const float*)d_in[10];
    const float* lnhb  = (const float*)d_in[11];
    const float* rlng  = (const float*)d_in[12];
    const float* rlnb  = (const float*)d_in[13];
    const float* rw1   = (const float*)d_in[14];
    const float* rb1   = (const float*)d_in[15];
    const float* rw2   = (const float*)d_in[16];
    const float* rb2   = (const float*)d_in[17];
    float* out = (float*)d_out;
    (void)in_sizes; (void)n_in; (void)out_size; (void)ws_size;

    char* base = (char*)d_ws;
    size_t off = 0;
    auto alloc = [&](size_t bytes) -> char* {
        char* p = base + off;
        off = (off + bytes + 255) & ~(size_t)255;
        return p;
    };
    u16*   xhi    = (u16*)alloc((size_t)T_ * D_ * 2);
    u16*   xlo    = (u16*)alloc((size_t)T_ * D_ * 2);
    u16*   whiT   = (u16*)alloc((size_t)D_ * D_ * 2);
    u16*   wloT   = (u16*)alloc((size_t)D_ * D_ * 2);
    float* c1part = (float*)alloc(32 * 1024 * 4);
    float* c2part = (float*)alloc(32 * 1024 * 4);
    float* c1     = (float*)alloc(1024 * 4);
    float* dvec   = (float*)alloc(1024 * 4);
    float* sx     = (float*)alloc((size_t)T_ * 4);
    float* sxx    = (float*)alloc((size_t)T_ * 4);
    float* ptv    = (float*)alloc((size_t)T_ * 4);
    float* qtv    = (float*)alloc((size_t)T_ * 4);
    float* gpart  = (float*)alloc((size_t)8 * 32 * 1024 * 4);
    float* hnew   = (float*)alloc(8 * 1024 * 4);
    float* vmat   = (float*)alloc(8 * 1024 * 4);
    float* shb    = (float*)alloc(256);
    float* shhb   = (float*)alloc(256);
    float* lpart  = (float*)alloc((size_t)8 * T_ * H_ * 4);
    float* entpart= (float*)alloc(1024 * 4);
    float* partA  = (float*)alloc((size_t)32 * 8 * 1024 * 4);   // xctrl partials, then vmat partials
    float* partB  = (float*)alloc((size_t)32 * 8 * 1024 * 4);   // z partials
    float* partC  = (float*)alloc((size_t)32 * 8 * 1024 * 4);   // h partials

    k01<<<768, 256, 0, stream>>>(x, xhi, xlo, sx, sxx, gpart,
                                 rw1, rlng, rlnb, whiT, wloT, c1part, c2part);
    kB<<<132, 256, 0, stream>>>(gpart, pg, pbv, inpw, partA,
                                c1part, c2part, rb1, c1, dvec);
    kgemv2_f<<<dim3(4, 32), 256, 0, stream>>>(partA, inpb, wzw, whw, partB, partC);
    k3b_red_ln<<<8, 256, 0, stream>>>(partB, partC, wzb, whb, state, lnhg, lnhb,
                                      hnew, out + (size_t)T_ * H_, shb, shhb);
    kE<<<192, 256, 0, stream>>>(hnew, rw1 + (size_t)1024 * 1024, rlng + 1024, partA,
                                sx, sxx, shb, shhb, ptv, qtv);
    kF<<<32, 256, 0, stream>>>(partA, vmat);
    k5_gemm<<<1024, 256, 0, stream>>>(xhi, xlo, whiT, wloT, ptv, qtv, vmat,
                                      c1, dvec, rw2, lpart);
    k6<<<1024, 256, 0, stream>>>(lpart, rb2, out, entpart);
    k7<<<1, 256, 0, stream>>>(entpart, out + (size_t)T_ * H_ + (size_t)B_ * D_);
}

// Round 10
// 193.840 us; speedup vs baseline: 1.3937x; 1.3937x over previous
//
#include <hip/hip_runtime.h>
#include <hip/hip_bf16.h>
#include <math.h>

typedef unsigned short u16;
typedef __attribute__((ext_vector_type(8))) short bf16x8;
typedef __attribute__((ext_vector_type(4))) float f32x4;
typedef __attribute__((ext_vector_type(4))) unsigned short u16x4;

#define B_ 8
#define S_ 2048
#define T_ 16384
#define D_ 1024
#define H_ 16
#define EPS_ 1e-5f

__device__ __forceinline__ u16 f2bf(float f) {
    __hip_bfloat16 h = __float2bfloat16(f);
    union { __hip_bfloat16 h; u16 u; } cv; cv.h = h; return cv.u;
}
__device__ __forceinline__ float bf2f(u16 u) {
    union { u16 u; __hip_bfloat16 h; } cv; cv.u = u; return __bfloat162float(cv.h);
}

// ---------- k01: fused {k1 pool-LN pass (blocks 0..255)} U {k0a W' split (blocks 256..767)} ----------
__global__ __launch_bounds__(256) void k01(const float* __restrict__ x,
        u16* __restrict__ xhi, u16* __restrict__ xlo,
        float* __restrict__ sx, float* __restrict__ sxx, float* __restrict__ gpart,
        const float* __restrict__ rw1, const float* __restrict__ rlng,
        const float* __restrict__ rlnb, u16* __restrict__ whiT, u16* __restrict__ wloT,
        float* __restrict__ c1part, float* __restrict__ c2part) {
    __shared__ float lacc[4][1024];                    // k1 use
    __shared__ float ld[64][65];                       // k0a use
    __shared__ float red[2][4][64];
    int blk = blockIdx.x;
    int tid = threadIdx.x;
    if (blk < 256) {
        // ----- k1: pool LN pass, per-token sums, x -> split bf16 -----
        int b = blk >> 5, chunk = blk & 31;
        int w = tid >> 6, lane = tid & 63;
        float acc[4][4];
        #pragma unroll
        for (int j = 0; j < 4; ++j)
            #pragma unroll
            for (int c = 0; c < 4; ++c) acc[j][c] = 0.f;
        for (int i = 0; i < 16; ++i) {
            int s = chunk * 64 + i * 4 + w;
            size_t tok = (size_t)b * S_ + s;
            size_t base = tok * D_;
            float4 v[4];
            float sum = 0.f, ssq = 0.f;
            #pragma unroll
            for (int j = 0; j < 4; ++j) {
                v[j] = *(const float4*)&x[base + j * 256 + lane * 4];
                sum += v[j].x + v[j].y + v[j].z + v[j].w;
                ssq += v[j].x * v[j].x + v[j].y * v[j].y + v[j].z * v[j].z + v[j].w * v[j].w;
            }
            #pragma unroll
            for (int m = 1; m < 64; m <<= 1) { sum += __shfl_xor(sum, m); ssq += __shfl_xor(ssq, m); }
            float mean = sum * (1.f / 1024.f);
            float var = ssq * (1.f / 1024.f) - mean * mean;
            float rstd = rsqrtf(var + EPS_);
            if (lane == 0) { sx[tok] = sum; sxx[tok] = ssq; }
            #pragma unroll
            for (int j = 0; j < 4; ++j) {
                float xs[4] = { v[j].x, v[j].y, v[j].z, v[j].w };
                u16 hs[4], ls[4];
                #pragma unroll
                for (int c = 0; c < 4; ++c) {
                    acc[j][c] += (xs[c] - mean) * rstd;
                    u16 h = f2bf(xs[c]);
                    hs[c] = h;
                    ls[c] = f2bf(xs[c] - bf2f(h));
                }
                size_t o = base + j * 256 + lane * 4;
                *(u16x4*)&xhi[o] = (u16x4){ hs[0], hs[1], hs[2], hs[3] };
                *(u16x4*)&xlo[o] = (u16x4){ ls[0], ls[1], ls[2], ls[3] };
            }
        }
        #pragma unroll
        for (int j = 0; j < 4; ++j)
            #pragma unroll
            for (int c = 0; c < 4; ++c) lacc[w][j * 256 + lane * 4 + c] = acc[j][c];
        __syncthreads();
        for (int q = 0; q < 4; ++q) {
            int n = q * 256 + tid;
            gpart[((size_t)b * 32 + chunk) * 1024 + n] =
                lacc[0][n] + lacc[1][n] + lacc[2][n] + lacc[3][n];
        }
    } else {
        // ----- k0a: W' transpose+split, c1/c2 partials -----
        int idx = blk - 256;
        int nb = idx & 15, kb = idx >> 4;
        int nl = tid & 63, kq = tid >> 6;
        int n0 = nb * 64, k0 = kb * 64;
        float a1 = 0.f, a2 = 0.f;
        #pragma unroll
        for (int r = 0; r < 16; ++r) {
            int kl = r * 4 + kq;
            int k = k0 + kl, n = n0 + nl;
            float w0 = rw1[(size_t)k * 1024 + n];
            ld[kl][nl] = w0;
            a1 += rlng[k] * w0;
            a2 += rlnb[k] * w0;
        }
        red[0][kq][nl] = a1;
        red[1][kq][nl] = a2;
        __syncthreads();
        if (tid < 64) {
            c1part[(size_t)kb * 1024 + n0 + tid] = red[0][0][tid] + red[0][1][tid] + red[0][2][tid] + red[0][3][tid];
            c2part[(size_t)kb * 1024 + n0 + tid] = red[1][0][tid] + red[1][1][tid] + red[1][2][tid] + red[1][3][tid];
        }
        if (kb < 16) {
            #pragma unroll
            for (int r = 0; r < 16; ++r) {
                int nl2 = r * 4 + kq;
                int k = k0 + nl, n = n0 + nl2;
                float w0 = ld[nl][nl2] * rlng[k];
                u16 hi = f2bf(w0);
                float lo = w0 - bf2f(hi);
                whiT[(size_t)n * 1024 + k] = hi;
                wloT[(size_t)n * 1024 + k] = f2bf(lo);
            }
        }
    }
}

// ---------- kB: {kgemv_g split-K GEMV (blocks 0..127)} U {c1/dvec reduce (128..131)} ----------
__global__ __launch_bounds__(256) void kB(const float* __restrict__ gpart,
        const float* __restrict__ pg, const float* __restrict__ pb,
        const float* __restrict__ W, float* __restrict__ part,
        const float* __restrict__ c1part, const float* __restrict__ c2part,
        const float* __restrict__ rb1, float* __restrict__ c1, float* __restrict__ dvec) {
    int blk = blockIdx.x, t = threadIdx.x;
    if (blk < 128) {
        int nBlk = blk & 3, ks = blk >> 2;
        int n = nBlk * 256 + t;
        int k0 = ks * 32;
        __shared__ float sg[8][32];
        {
            int b = t >> 5, k = t & 31;
            float s = 0.f;
            #pragma unroll 8
            for (int p = 0; p < 32; ++p) s += gpart[((size_t)b * 32 + p) * 1024 + k0 + k];
            sg[b][k] = s * (1.f / 2048.f) * pg[k0 + k] + pb[k0 + k];
        }
        __syncthreads();
        float acc[8] = {};
        #pragma unroll
        for (int k = 0; k < 32; ++k) {
            float wv = W[(size_t)(k0 + k) * 1024 + n];
            #pragma unroll
            for (int b = 0; b < 8; ++b) acc[b] += sg[b][k] * wv;
        }
        #pragma unroll
        for (int b = 0; b < 8; ++b)
            part[((size_t)ks * 8 + b) * 1024 + n] = acc[b];
    } else {
        int n = (blk - 128) * 256 + t;
        float s1 = 0.f, s2 = 0.f;
        for (int p = 0; p < 32; ++p) { s1 += c1part[p * 1024 + n]; s2 += c2part[p * 1024 + n]; }
        c1[n] = s1;
        dvec[n] = s2 + rb1[n];
    }
}

// ---------- kgemv2_f: fused xctrl reduce(+bias) + dual split-K GEMV for W_z / W_h ----------
__global__ __launch_bounds__(256) void kgemv2_f(const float* __restrict__ partIn,
        const float* __restrict__ bias,
        const float* __restrict__ Wz, const float* __restrict__ Wh,
        float* __restrict__ zpart, float* __restrict__ hpart) {
    int t = threadIdx.x;
    int n = blockIdx.x * 256 + t;
    int k0 = blockIdx.y * 32;
    __shared__ float sg[8][32];
    {
        int b = t >> 5, k = t & 31;
        float s = bias[k0 + k];
        #pragma unroll 8
        for (int p = 0; p < 32; ++p) s += partIn[((size_t)p * 8 + b) * 1024 + k0 + k];
        sg[b][k] = s;
    }
    __syncthreads();
    float az[8] = {}, ah[8] = {};
    #pragma unroll
    for (int k = 0; k < 32; ++k) {
        size_t o = (size_t)(k0 + k) * 1024 + n;
        float wz = Wz[o];
        float wh = Wh[o];
        #pragma unroll
        for (int b = 0; b < 8; ++b) { az[b] += sg[b][k] * wz; ah[b] += sg[b][k] * wh; }
    }
    #pragma unroll
    for (int b = 0; b < 8; ++b) {
        size_t o = ((size_t)blockIdx.y * 8 + b) * 1024 + n;
        zpart[o] = az[b];
        hpart[o] = ah[b];
    }
}

// ---------- k3b reduce + gate + h-LayerNorm fused (grid 8, one block per b) ----------
__global__ __launch_bounds__(256) void k3b_red_ln(const float* __restrict__ zpart,
        const float* __restrict__ hpart, const float* __restrict__ bz,
        const float* __restrict__ bh, const float* __restrict__ state,
        const float* __restrict__ lg, const float* __restrict__ lb,
        float* __restrict__ hnew, float* __restrict__ outh,
        float* __restrict__ shb, float* __restrict__ shhb) {
    int b = blockIdx.x, tid = threadIdx.x;
    int w = tid >> 6, lane = tid & 63;
    __shared__ float rbuf[4][2];
    float hp[4];
    float sum = 0.f, ssq = 0.f;
    #pragma unroll
    for (int q = 0; q < 4; ++q) {
        int n = q * 256 + tid;
        float az = bz[n], ah = bh[n];
        #pragma unroll 8
        for (int p = 0; p < 32; ++p) {
            size_t o = ((size_t)p * 8 + b) * 1024 + n;
            az += zpart[o];
            ah += hpart[o];
        }
        float z = 1.f / (1.f + expf(-az));
        float hc = tanhf(ah);
        float v = (1.f - z) * state[(size_t)b * 1024 + n] + z * hc;
        hp[q] = v; sum += v; ssq += v * v;
    }
    #pragma unroll
    for (int m = 1; m < 64; m <<= 1) { sum += __shfl_xor(sum, m); ssq += __shfl_xor(ssq, m); }
    if (lane == 0) { rbuf[w][0] = sum; rbuf[w][1] = ssq; }
    __syncthreads();
    sum = rbuf[0][0] + rbuf[1][0] + rbuf[2][0] + rbuf[3][0];
    ssq = rbuf[0][1] + rbuf[1][1] + rbuf[2][1] + rbuf[3][1];
    float mean = sum * (1.f / 1024.f);
    float var = ssq * (1.f / 1024.f) - mean * mean;
    float rstd = rsqrtf(var + EPS_);
    float s2 = 0.f, q2 = 0.f;
    #pragma unroll
    for (int q = 0; q < 4; ++q) {
        int n = q * 256 + tid;
        float h = (hp[q] - mean) * rstd * lg[n] + lb[n];
        hnew[(size_t)b * 1024 + n] = h;
        outh[(size_t)b * 1024 + n] = h;
        s2 += h; q2 += h * h;
    }
    #pragma unroll
    for (int m = 1; m < 64; m <<= 1) { s2 += __shfl_xor(s2, m); q2 += __shfl_xor(q2, m); }
    __syncthreads();
    if (lane == 0) { rbuf[w][0] = s2; rbuf[w][1] = q2; }
    __syncthreads();
    if (tid == 0) {
        shb[b] = rbuf[0][0] + rbuf[1][0] + rbuf[2][0] + rbuf[3][0];
        shhb[b] = rbuf[0][1] + rbuf[1][1] + rbuf[2][1] + rbuf[3][1];
    }
}

// ---------- kE: {kgemv_split vmat partials (blocks 0..127)} U {pt/qt (128..191)} ----------
__global__ __launch_bounds__(256) void kE(const float* __restrict__ in,
        const float* __restrict__ W, const float* __restrict__ scale,
        float* __restrict__ part,
        const float* __restrict__ sx, const float* __restrict__ sxx,
        const float* __restrict__ shb, const float* __restrict__ shhb,
        float* __restrict__ pt, float* __restrict__ qt) {
    int blk = blockIdx.x, t = threadIdx.x;
    if (blk < 128) {
        int nBlk = blk & 3, ks = blk >> 2;
        int n = nBlk * 256 + t;
        int k0 = ks * 32;
        __shared__ float sg[8][32];
        {
            int b = t >> 5, k = t & 31;
            sg[b][k] = in[b * 1024 + k0 + k] * scale[k0 + k];
        }
        __syncthreads();
        float acc[8] = {};
        #pragma unroll
        for (int k = 0; k < 32; ++k) {
            float wv = W[(size_t)(k0 + k) * 1024 + n];
            #pragma unroll
            for (int b = 0; b < 8; ++b) acc[b] += sg[b][k] * wv;
        }
        #pragma unroll
        for (int b = 0; b < 8; ++b)
            part[((size_t)ks * 8 + b) * 1024 + n] = acc[b];
    } else {
        int tok = (blk - 128) * 256 + t;
        int b = tok >> 11;
        float m = (sx[tok] + shb[b]) * (1.f / 2048.f);
        float var = (sxx[tok] + shhb[b]) * (1.f / 2048.f) - m * m;
        float rstd = rsqrtf(var + EPS_);
        pt[tok] = rstd;
        qt[tok] = -m * rstd;
    }
}

// ---------- kF: vmat = reduce vmat partials (grid 32) ----------
__global__ __launch_bounds__(256) void kF(const float* __restrict__ part,
        float* __restrict__ vmat) {
    int i = blockIdx.x * 256 + threadIdx.x;
    int b = i >> 10, n = i & 1023;
    float s = 0.f;
    #pragma unroll 8
    for (int p = 0; p < 32; ++p) s += part[((size_t)p * 8 + b) * 1024 + n];
    vmat[i] = s;
}

// ---------- K5 (round-8 exact: 4-plane staging + swizzle + XCD remap):
//   split-bf16 MFMA GEMM u = x @ W', 128x128 tile, BK=64, 2-barrier K-loop ----------
__device__ __forceinline__ void gl16(const void* g, void* l) {
    __builtin_amdgcn_global_load_lds((const __attribute__((address_space(1))) void*)g,
                                     (__attribute__((address_space(3))) void*)l, 16, 0, 0);
}

__global__ __launch_bounds__(256, 1) void k5_gemm(
        const u16* __restrict__ xhi, const u16* __restrict__ xlo,
        const u16* __restrict__ whiT, const u16* __restrict__ wloT,
        const float* __restrict__ pt, const float* __restrict__ qt,
        const float* __restrict__ vmat, const float* __restrict__ c1,
        const float* __restrict__ dvec, const float* __restrict__ rw2,
        float* __restrict__ lpart) {
    __shared__ unsigned char smem[66048];
    u16* sAh = (u16*)smem;
    u16* sAl = sAh + 128 * 64;
    u16* sBh = sAl + 128 * 64;
    u16* sBl = sBh + 128 * 64;
    float* shid = (float*)smem;   // reused after main loop: [128][129]

    // XCD-bijective remap: XCD x = bid%8 handles mb in [x*16, x*16+16), all nb.
    int bid = blockIdx.x;                   // 1024
    int x8 = bid & 7, j = bid >> 3;
    int mb = x8 * 16 + (j >> 3);            // 0..127
    int nb = j & 7;                         // 0..7
    int tid = threadIdx.x;
    int lane = tid & 63, wid = tid >> 6;
    int wm = wid >> 1, wn = wid & 1;
    int l16 = lane & 15, lq = lane >> 4;

    f32x4 acc[4][4] = {};

    size_t aBase = (size_t)mb * 128 * 1024;
    size_t bBase = (size_t)nb * 128 * 1024;

    for (int kb = 0; kb < 16; ++kb) {
        __syncthreads();
        #pragma unroll
        for (int i = 0; i < 4; ++i) {
            int chunk = tid + 256 * i;
            int row = chunk >> 3, c8 = chunk & 7;
            int s8 = c8 ^ (row & 7);            // involution slot-swizzle (16B granules)
            size_t go = (size_t)row * 1024 + (size_t)kb * 64 + s8 * 8;
            int lo = chunk * 16;                // linear LDS dest (gl16 constraint)
            gl16(xhi + aBase + go, (char*)sAh + lo);
            gl16(xlo + aBase + go, (char*)sAl + lo);
            gl16(whiT + bBase + go, (char*)sBh + lo);
            gl16(wloT + bBase + go, (char*)sBl + lo);
        }
        asm volatile("s_waitcnt vmcnt(0)" ::: "memory");
        __syncthreads();
        #pragma unroll
        for (int kk = 0; kk < 2; ++kk) {
            bf16x8 ah[4], al[4], bh[4], bl[4];
            // swizzled read slot: within a frag, row&7 == l16&7
            int sl = ((kk * 4 + lq) ^ (l16 & 7)) * 8;
            #pragma unroll
            for (int f = 0; f < 4; ++f) {
                int ar = wm * 64 + f * 16 + l16;
                int br = wn * 64 + f * 16 + l16;
                ah[f] = *(const bf16x8*)&sAh[ar * 64 + sl];
                al[f] = *(const bf16x8*)&sAl[ar * 64 + sl];
                bh[f] = *(const bf16x8*)&sBh[br * 64 + sl];
                bl[f] = *(const bf16x8*)&sBl[br * 64 + sl];
            }
            #pragma unroll
            for (int mf = 0; mf < 4; ++mf)
                #pragma unroll
                for (int nf = 0; nf < 4; ++nf) {
                    acc[mf][nf] = __builtin_amdgcn_mfma_f32_16x16x32_bf16(ah[mf], bh[nf], acc[mf][nf], 0, 0, 0);
                    acc[mf][nf] = __builtin_amdgcn_mfma_f32_16x16x32_bf16(ah[mf], bl[nf], acc[mf][nf], 0, 0, 0);
                    acc[mf][nf] = __builtin_amdgcn_mfma_f32_16x16x32_bf16(al[mf], bh[nf], acc[mf][nf], 0, 0, 0);
                }
        }
    }
    __syncthreads();

    // epilogue: hid = gelu(pt*(u+v) + qt*c1 + dvec) -> LDS
    int token0 = mb * 128;
    int bidx = token0 >> 11;
    const float* vrow = vmat + (size_t)bidx * 1024;
    float vn[4], c1n[4], dn[4];
    #pragma unroll
    for (int nf = 0; nf < 4; ++nf) {
        int n = nb * 128 + wn * 64 + nf * 16 + l16;
        vn[nf] = vrow[n]; c1n[nf] = c1[n]; dn[nf] = dvec[n];
    }
    #pragma unroll
    for (int mf = 0; mf < 4; ++mf) {
        #pragma unroll
        for (int r = 0; r < 4; ++r) {
            int rowl = wm * 64 + mf * 16 + lq * 4 + r;
            float p = pt[token0 + rowl];
            float q = qt[token0 + rowl];
            #pragma unroll
            for (int nf = 0; nf < 4; ++nf) {
                int coll = wn * 64 + nf * 16 + l16;
                float pre = p * (acc[mf][nf][r] + vn[nf]) + q * c1n[nf] + dn[nf];
                float hid = 0.5f * pre * (1.f + erff(pre * 0.70710678118f));
                shid[rowl * 129 + coll] = hid;
            }
        }
    }
    __syncthreads();

    // partial logits for this N-block: [128 tokens][16 heads]
    int r2 = tid >> 1, half = tid & 1;
    const float* w2b = rw2 + (size_t)nb * 128 * 16 + half * 8;
    float a8[8];
    #pragma unroll
    for (int h = 0; h < 8; ++h) a8[h] = 0.f;
    #pragma unroll 8
    for (int j2 = 0; j2 < 128; ++j2) {
        float hv = shid[r2 * 129 + j2];
        float4 w0 = *(const float4*)(w2b + (size_t)j2 * 16);
        float4 w1 = *(const float4*)(w2b + (size_t)j2 * 16 + 4);
        a8[0] += hv * w0.x; a8[1] += hv * w0.y; a8[2] += hv * w0.z; a8[3] += hv * w0.w;
        a8[4] += hv * w1.x; a8[5] += hv * w1.y; a8[6] += hv * w1.z; a8[7] += hv * w1.w;
    }
    float* lp = lpart + ((size_t)nb * T_ + token0 + r2) * 16 + half * 8;
    #pragma unroll
    for (int h = 0; h < 8; ++h) lp[h] = a8[h];
}

// ---------- K6: sum partials -> logits -> softmax -> top4 renorm -> alpha, entropy partials ----------
__global__ __launch_bounds__(256) void k6(const float* __restrict__ lpart,
        const float* __restrict__ rb2, float* __restrict__ alpha_out,
        float* __restrict__ entpart) {
    int blk = blockIdx.x;   // 1024
    int tid = threadIdx.x;
    int token = blk * 16 + (tid >> 4);
    int h = tid & 15;
    float lg = rb2[h];
    #pragma unroll
    for (int p = 0; p < 8; ++p) lg += lpart[((size_t)p * T_ + token) * 16 + h];

    float mx = lg;
    #pragma unroll
    for (int m = 1; m < 16; m <<= 1) mx = fmaxf(mx, __shfl_xor(mx, m));
    float e = expf(lg - mx);
    float sum = e;
    #pragma unroll
    for (int m = 1; m < 16; m <<= 1) sum += __shfl_xor(sum, m);
    float a0 = e / sum;

    float work = lg;
    bool sel = false;
    #pragma unroll
    for (int it = 0; it < 4; ++it) {
        float bv = work; int bi = h;
        #pragma unroll
        for (int m = 1; m < 16; m <<= 1) {
            float ov = __shfl_xor(bv, m); int oi = __shfl_xor(bi, m);
            if (ov > bv || (ov == bv && oi < bi)) { bv = ov; bi = oi; }
        }
        if (h == bi) { sel = true; work = -1e30f; }
    }
    float am = sel ? a0 : 0.f;
    float den = am;
    #pragma unroll
    for (int m = 1; m < 16; m <<= 1) den += __shfl_xor(den, m);
    den = fmaxf(den, 1e-12f);
    float a = am / den;
    alpha_out[(size_t)token * 16 + h] = a;

    float term = a * logf(fmaxf(a, 1e-12f));
    #pragma unroll
    for (int m = 1; m < 64; m <<= 1) term += __shfl_xor(term, m);
    __shared__ float tw[4];
    if ((tid & 63) == 0) tw[tid >> 6] = term;
    __syncthreads();
    if (tid == 0) entpart[blk] = tw[0] + tw[1] + tw[2] + tw[3];
}

// ---------- K7: entropy finalize ----------
__global__ __launch_bounds__(256) void k7(const float* __restrict__ entpart,
        float* __restrict__ out_ent) {
    int tid = threadIdx.x;
    float s = 0.f;
    for (int i = tid; i < 1024; i += 256) s += entpart[i];
    #pragma unroll
    for (int m = 1; m < 64; m <<= 1) s += __shfl_xor(s, m);
    __shared__ float tw[4];
    if ((tid & 63) == 0) tw[tid >> 6] = s;
    __syncthreads();
    if (tid == 0) out_ent[0] = -(tw[0] + tw[1] + tw[2] + tw[3]) * (1.f / (float)T_);
}

extern "C" void kernel_launch(void* const* d_in, const int* in_sizes, int n_in,
                              void* d_out, int out_size, void* d_ws, size_t ws_size,
                              hipStream_t stream) {
    const float* x     = (const float*)d_in[0];
    const float* state = (const float*)d_in[1];
    const float* pg    = (const float*)d_in[2];
    const float* pbv   = (const float*)d_in[3];
    const float* inpw  = (const float*)d_in[4];
    const float* inpb  = (const float*)d_in[5];
    const float* wzw   = (const float*)d_in[6];
    const float* wzb   = (const float*)d_in[7];
    const float* whw   = (const float*)d_in[8];
    const float* whb   = (const float*)d_in[9];
    const float* lnhg  = (const float*)d_in[10];
    const float* lnhb  = (const float*)d_in[11];
    const float* rlng  = (const float*)d_in[12];
    const float* rlnb  = (const float*)d_in[13];
    const float* rw1   = (const float*)d_in[14];
    const float* rb1   = (const float*)d_in[15];
    const float* rw2   = (const float*)d_in[16];
    const float* rb2   = (const float*)d_in[17];
    float* out = (float*)d_out;
    (void)in_sizes; (void)n_in; (void)out_size; (void)ws_size;

    char* base = (char*)d_ws;
    size_t off = 0;
    auto alloc = [&](size_t bytes) -> char* {
        char* p = base + off;
        off = (off + bytes + 255) & ~(size_t)255;
        return p;
    };
    u16*   xhi    = (u16*)alloc((size_t)T_ * D_ * 2);
    u16*   xlo    = (u16*)alloc((size_t)T_ * D_ * 2);
    u16*   whiT   = (u16*)alloc((size_t)D_ * D_ * 2);
    u16*   wloT   = (u16*)alloc((size_t)D_ * D_ * 2);
    float* c1part = (float*)alloc(32 * 1024 * 4);
    float* c2part = (float*)alloc(32 * 1024 * 4);
    float* c1     = (float*)alloc(1024 * 4);
    float* dvec   = (float*)alloc(1024 * 4);
    float* sx     = (float*)alloc((size_t)T_ * 4);
    float* sxx    = (float*)alloc((size_t)T_ * 4);
    float* ptv    = (float*)alloc((size_t)T_ * 4);
    float* qtv    = (float*)alloc((size_t)T_ * 4);
    float* gpart  = (float*)alloc((size_t)8 * 32 * 1024 * 4);
    float* hnew   = (float*)alloc(8 * 1024 * 4);
    float* vmat   = (float*)alloc(8 * 1024 * 4);
    float* shb    = (float*)alloc(256);
    float* shhb   = (float*)alloc(256);
    float* lpart  = (float*)alloc((size_t)8 * T_ * H_ * 4);
    float* entpart= (float*)alloc(1024 * 4);
    float* partA  = (float*)alloc((size_t)32 * 8 * 1024 * 4);   // xctrl partials, then vmat partials
    float* partB  = (float*)alloc((size_t)32 * 8 * 1024 * 4);   // z partials
    float* partC  = (float*)alloc((size_t)32 * 8 * 1024 * 4);   // h partials

    k01<<<768, 256, 0, stream>>>(x, xhi, xlo, sx, sxx, gpart,
                                 rw1, rlng, rlnb, whiT, wloT, c1part, c2part);
    kB<<<132, 256, 0, stream>>>(gpart, pg, pbv, inpw, partA,
                                c1part, c2part, rb1, c1, dvec);
    kgemv2_f<<<dim3(4, 32), 256, 0, stream>>>(partA, inpb, wzw, whw, partB, partC);
    k3b_red_ln<<<8, 256, 0, stream>>>(partB, partC, wzb, whb, state, lnhg, lnhb,
                                      hnew, out + (size_t)T_ * H_, shb, shhb);
    kE<<<192, 256, 0, stream>>>(hnew, rw1 + (size_t)1024 * 1024, rlng + 1024, partA,
                                sx, sxx, shb, shhb, ptv, qtv);
    kF<<<32, 256, 0, stream>>>(partA, vmat);
    k5_gemm<<<1024, 256, 0, stream>>>(xhi, xlo, whiT, wloT, ptv, qtv, vmat,
                                      c1, dvec, rw2, lpart);
    k6<<<1024, 256, 0, stream>>>(lpart, rb2, out, entpart);
    k7<<<1, 256, 0, stream>>>(entpart, out + (size_t)T_ * H_ + (size_t)B_ * D_);
}